// Round 2
// baseline (2116.236 us; speedup 1.0000x reference)
//
#include <hip/hip_runtime.h>
#include <math.h>

// SwinTransformerBlock: B=2,D=8,H=56,W=56,C=384, win=(2,7,7), shift=(1,3,3)
#define TOK   50176      // total tokens
#define CDIM  384
#define NTOK  98         // tokens per window
#define NHEAD 12
#define HD    32
#define MLPH  1536
#define QKVN  1152

typedef __attribute__((ext_vector_type(8))) short s16x8;
typedef __attribute__((ext_vector_type(4))) float f32x4;

// fp32 -> bf16 (RNE) helpers, manual to stay self-contained
__device__ __forceinline__ unsigned short bf_hi(float x) {
  unsigned u = __float_as_uint(x);
  return (unsigned short)((u + 0x7fffu + ((u >> 16) & 1u)) >> 16);
}
__device__ __forceinline__ float bf_f(unsigned short h) {
  return __uint_as_float(((unsigned)h) << 16);
}

// token id (window-major) -> spatial row id. Serves forward gather
// (LN1+shift+partition) and reverse scatter (window_reverse+roll).
__device__ __forceinline__ long token_to_spatial(int t) {
  int Bidx = t / NTOK;
  int n = t % NTOK;
  int b_ = Bidx >> 8;
  int widx = Bidx & 255;
  int wd = widx >> 6, wh = (widx >> 3) & 7, ww = widx & 7;
  int nd = n / 49, nh = (n % 49) / 7, nw = n % 7;
  int dd = (wd * 2 + nd + 1) & 7;
  int hh = (wh * 7 + nh + 3) % 56;
  int wc = (ww * 7 + nw + 3) % 56;
  return ((long)(b_ * 8 + dd) * 56 + hh) * 56 + wc;
}

// ---- LayerNorm -> bf16 hi/lo planes. GATHER=1: permuted source (LN1) ----
template <int GATHER>
__global__ __launch_bounds__(256) void k_ln_bf(const float* __restrict__ x,
    const float* __restrict__ g, const float* __restrict__ bb,
    unsigned short* __restrict__ oh, unsigned short* __restrict__ ol) {
  int row = blockIdx.x * 4 + (threadIdx.x >> 6);
  int lane = threadIdx.x & 63;
  long srow = GATHER ? token_to_spatial(row) : (long)row;
  const float* src = x + srow * CDIM;
  float v[6]; float sum = 0.f, sq = 0.f;
#pragma unroll
  for (int i = 0; i < 6; i++) { float t = src[lane + i * 64]; v[i] = t; sum += t; sq += t * t; }
#pragma unroll
  for (int o = 1; o < 64; o <<= 1) { sum += __shfl_xor(sum, o); sq += __shfl_xor(sq, o); }
  float mean = sum * (1.f / 384.f);
  float rstd = rsqrtf(sq * (1.f / 384.f) - mean * mean + 1e-5f);
  long ob = (long)row * CDIM;
#pragma unroll
  for (int i = 0; i < 6; i++) {
    int c = lane + i * 64;
    float y = (v[i] - mean) * rstd * g[c] + bb[c];
    unsigned short h = bf_hi(y);
    oh[ob + c] = h; ol[ob + c] = bf_hi(y - bf_f(h));
  }
}

// ---- weight split+transpose: W fp32 [K][N] -> Th/Tl bf16 [N][K] ----
__global__ __launch_bounds__(256) void k_wsplit(const float* __restrict__ W,
    unsigned short* __restrict__ Th, unsigned short* __restrict__ Tl, int K, int N) {
  long idx = (long)blockIdx.x * 256 + threadIdx.x;   // n*K + k
  int n = (int)(idx / K);
  int k = (int)(idx - (long)n * K);
  float v = W[(long)k * N + n];
  unsigned short h = bf_hi(v);
  Th[idx] = h; Tl[idx] = bf_hi(v - bf_f(h));
}

// ---- split-bf16 MFMA GEMM: C = A @ B^T_stored (+bias, epilogue variants)
// A: hi/lo bf16 [rows][K]; B: hi/lo bf16 [N][K] (pre-transposed weights).
// 128x128 tile, BK=32, 4 waves (2x2), 4x4 16x16x32 frags per wave.
// EPI: 0=+bias->f32   1=+bias,gelu->hi/lo   2=+bias,scatter t2s,+res->f32
//      3=+bias,+res(row_base offset)->f32
template <int EPI>
__global__ __launch_bounds__(256, 2) void k_mfma(
    const unsigned short* __restrict__ Ah, const unsigned short* __restrict__ Al,
    const unsigned short* __restrict__ Bh, const unsigned short* __restrict__ Bl,
    const float* __restrict__ bias, int Nn, int Kk,
    float* __restrict__ outf, unsigned short* __restrict__ outh,
    unsigned short* __restrict__ outl, const float* __restrict__ resp, long row_base) {
  __shared__ unsigned short As[2][128][32];
  __shared__ unsigned short Bs[2][128][32];
  int tid = threadIdx.x;
  int sel = tid >> 6, ln = tid & 63;
  int lr = tid & 15, lg = (tid & 63) >> 4;
  int wr = sel >> 1, wc = sel & 1;
  const unsigned short* gsrc = (sel == 0) ? Ah : (sel == 1) ? Al : (sel == 2) ? Bh : Bl;
  long grow0 = (sel < 2) ? (long)blockIdx.x * 128 : (long)blockIdx.y * 128;
  unsigned short (*ldst)[32] = (sel == 0) ? As[0] : (sel == 1) ? As[1]
                             : (sel == 2) ? Bs[0] : Bs[1];
  f32x4 acc[4][4];
#pragma unroll
  for (int i = 0; i < 4; i++)
#pragma unroll
    for (int j = 0; j < 4; j++) acc[i][j] = (f32x4){0.f, 0.f, 0.f, 0.f};

  int swz = (ln >> 1) & 3;                 // staging row swizzle (rows ln, ln+64)
  int co = ((lg ^ ((lr >> 1) & 3)) << 3);  // fragment-read swizzled k-chunk

  for (int k0 = 0; k0 < Kk; k0 += 32) {
#pragma unroll
    for (int h = 0; h < 2; h++) {
      int m = ln + (h << 6);
      const unsigned short* src = gsrc + (grow0 + m) * (long)Kk + k0;
#pragma unroll
      for (int c = 0; c < 4; c++) {
        s16x8 v = *(const s16x8*)(src + (c << 3));
        *(s16x8*)&ldst[m][((c ^ swz) << 3)] = v;
      }
    }
    __syncthreads();
    s16x8 fa[2][4], fb[2][4];
#pragma unroll
    for (int i = 0; i < 4; i++) {
      int r = wr * 64 + i * 16 + lr;
      fa[0][i] = *(const s16x8*)&As[0][r][co];
      fa[1][i] = *(const s16x8*)&As[1][r][co];
      int n = wc * 64 + i * 16 + lr;
      fb[0][i] = *(const s16x8*)&Bs[0][n][co];
      fb[1][i] = *(const s16x8*)&Bs[1][n][co];
    }
#pragma unroll
    for (int i = 0; i < 4; i++)
#pragma unroll
      for (int j = 0; j < 4; j++) {   // (Ah+Al)(Bh+Bl) ~= AhBh + AhBl + AlBh
        acc[i][j] = __builtin_amdgcn_mfma_f32_16x16x32_bf16(fa[0][i], fb[0][j], acc[i][j], 0, 0, 0);
        acc[i][j] = __builtin_amdgcn_mfma_f32_16x16x32_bf16(fa[0][i], fb[1][j], acc[i][j], 0, 0, 0);
        acc[i][j] = __builtin_amdgcn_mfma_f32_16x16x32_bf16(fa[1][i], fb[0][j], acc[i][j], 0, 0, 0);
      }
    __syncthreads();
  }
  // epilogue: D row = wr*64+i*16+lg*4+q, col = wc*64+j*16+lr  (m89 layout)
  int colb = blockIdx.y * 128 + wc * 64;
  float bv[4];
#pragma unroll
  for (int j = 0; j < 4; j++) bv[j] = bias[colb + j * 16 + lr];
#pragma unroll
  for (int i = 0; i < 4; i++) {
#pragma unroll
    for (int q = 0; q < 4; q++) {
      long rl = (long)blockIdx.x * 128 + wr * 64 + i * 16 + lg * 4 + q;
      long obase;
      if constexpr (EPI == 2) obase = token_to_spatial((int)rl) * 384;
      else                    obase = (row_base + rl) * (long)Nn;
#pragma unroll
      for (int j = 0; j < 4; j++) {
        int cg = colb + j * 16 + lr;
        float v = acc[i][j][q] + bv[j];
        if constexpr (EPI == 0) {
          outf[obase + cg] = v;
        } else if constexpr (EPI == 1) {
          v = 0.5f * v * (1.f + erff(v * 0.70710678118654752f));
          unsigned short hh = bf_hi(v);
          outh[obase + cg] = hh; outl[obase + cg] = bf_hi(v - bf_f(hh));
        } else {
          outf[obase + cg] = v + resp[obase + cg];
        }
      }
    }
  }
}

// ---- windowed attention (fp32), one (window, head) per block ----
__global__ __launch_bounds__(256) void k_attn(const float* __restrict__ qkv,
    const float* __restrict__ mask, const float* __restrict__ btab,
    unsigned short* __restrict__ AWh, unsigned short* __restrict__ AWl, int win_base) {
  __shared__ float sQ[NTOK][HD + 1];
  __shared__ float sK[NTOK][HD + 1];
  __shared__ float sV[NTOK][HD + 1];
  __shared__ float sS[NTOK][NTOK + 1];
  int head = blockIdx.x % NHEAD;
  int w_loc = blockIdx.x / NHEAD;
  int w_glob = win_base + w_loc;
  int tid = threadIdx.x;
  const float scale = 0.1767766952966369f;  // 32^-0.5
  long base = (long)w_loc * NTOK * QKVN + head * HD;
  for (int idx = tid; idx < NTOK * HD; idx += 256) {
    int n = idx >> 5, d = idx & 31;
    long p = base + (long)n * QKVN + d;
    sQ[n][d] = qkv[p] * scale;
    sK[n][d] = qkv[p + CDIM];
    sV[n][d] = qkv[p + 2 * CDIM];
  }
  __syncthreads();
  const float* mrow = mask + (long)(w_glob & 255) * NTOK * NTOK;
  for (int p = tid; p < NTOK * NTOK; p += 256) {
    int n = p / NTOK, m = p % NTOK;
    float s = 0.f;
#pragma unroll
    for (int d = 0; d < HD; d++) s = fmaf(sQ[n][d], sK[m][d], s);
    int nd = n / 49, nh = (n % 49) / 7, nw = n % 7;
    int md = m / 49, mh = (m % 49) / 7, mw = m % 7;
    int rel = (nd - md + 1) * 169 + (nh - mh + 6) * 13 + (nw - mw + 6);
    s += btab[rel * NHEAD + head] + mrow[p];
    sS[n][m] = s;
  }
  __syncthreads();
  if (tid < NTOK) {
    float mx = -1e30f;
    for (int m = 0; m < NTOK; m++) mx = fmaxf(mx, sS[tid][m]);
    float sum = 0.f;
    for (int m = 0; m < NTOK; m++) { float e = expf(sS[tid][m] - mx); sS[tid][m] = e; sum += e; }
    float inv = 1.f / sum;
    for (int m = 0; m < NTOK; m++) sS[tid][m] *= inv;
  }
  __syncthreads();
  for (int p = tid; p < NTOK * HD; p += 256) {
    int n = p >> 5, d = p & 31;
    float o = 0.f;
    for (int m = 0; m < NTOK; m++) o = fmaf(sS[n][m], sV[m][d], o);
    long t = (long)w_glob * NTOK + n;
    long adr = t * CDIM + head * HD + d;
    unsigned short hh = bf_hi(o);
    AWh[adr] = hh; AWl[adr] = bf_hi(o - bf_f(hh));
  }
}

extern "C" void kernel_launch(void* const* d_in, const int* in_sizes, int n_in,
                              void* d_out, int out_size, void* d_ws, size_t ws_size,
                              hipStream_t stream) {
  const float* x     = (const float*)d_in[0];
  const float* mask  = (const float*)d_in[1];
  const float* n1g   = (const float*)d_in[2];
  const float* n1b   = (const float*)d_in[3];
  const float* qkvw  = (const float*)d_in[4];
  const float* qkvb  = (const float*)d_in[5];
  const float* btab  = (const float*)d_in[6];
  const float* projw = (const float*)d_in[7];
  const float* projb = (const float*)d_in[8];
  const float* n2g   = (const float*)d_in[9];
  const float* n2b   = (const float*)d_in[10];
  const float* fc1w  = (const float*)d_in[11];
  const float* fc1b  = (const float*)d_in[12];
  const float* fc2w  = (const float*)d_in[13];
  const float* fc2b  = (const float*)d_in[14];
  float* out = (float*)d_out;

  // ws layout: [XW/AW/XN2 hi+lo planes: 4*S1 B][QKV-chunk f32 | H-chunk hi/lo][W planes]
  const long S1 = (long)TOK * CDIM;
  char* b0 = (char*)d_ws;
  unsigned short* XWh = (unsigned short*)b0;
  unsigned short* XWl = XWh + S1;
  const long WELEMS = 442368L + 147456L + 589824L + 589824L;
  int NC = 4;
  if ((size_t)(4 * S1 + (long)(TOK / 4) * MLPH * 4 + WELEMS * 4) > ws_size) NC = 8;
  const int CH = TOK / NC;                    // rows per chunk (mult of 128 and 98)
  char* bB = b0 + 4 * S1;
  float* QKVb = (float*)bB;
  unsigned short* Hh = (unsigned short*)bB;
  unsigned short* Hl = Hh + (long)CH * MLPH;
  unsigned short* pW = (unsigned short*)(bB + (long)CH * MLPH * 4);
  unsigned short* Wqh = pW,            *Wql = Wqh + 442368;
  unsigned short* Wph = Wql + 442368,  *Wpl = Wph + 147456;
  unsigned short* W1h = Wpl + 147456,  *W1l = W1h + 589824;
  unsigned short* W2h = W1l + 589824,  *W2l = W2h + 589824;

  // weight split+transpose (cheap, L2-resident)
  k_wsplit<<<1728, 256, 0, stream>>>(qkvw, Wqh, Wql, 384, 1152);
  k_wsplit<<<576, 256, 0, stream>>>(projw, Wph, Wpl, 384, 384);
  k_wsplit<<<2304, 256, 0, stream>>>(fc1w, W1h, W1l, 384, 1536);
  k_wsplit<<<2304, 256, 0, stream>>>(fc2w, W2h, W2l, 1536, 384);
  // LN1 + shift + window-partition gather -> XW planes
  k_ln_bf<1><<<TOK / 4, 256, 0, stream>>>(x, n1g, n1b, XWh, XWl);
  // attention path, chunked: qkv GEMM -> windowed attn (AW overwrites XW rows)
  for (int c = 0; c < NC; c++) {
    long r0 = (long)c * CH;
    k_mfma<0><<<dim3(CH / 128, 9), 256, 0, stream>>>(XWh + r0 * CDIM, XWl + r0 * CDIM,
        Wqh, Wql, qkvb, QKVN, CDIM, QKVb, nullptr, nullptr, nullptr, 0);
    k_attn<<<(CH / NTOK) * NHEAD, 256, 0, stream>>>(QKVb, mask, btab, XWh, XWl, (int)(r0 / NTOK));
  }
  // proj + window_reverse + roll + residual(x) -> d_out (spatial order)
  k_mfma<2><<<dim3(TOK / 128, 3), 256, 0, stream>>>(XWh, XWl, Wph, Wpl, projb,
      CDIM, CDIM, out, nullptr, nullptr, x, 0);
  // LN2 -> XN2 planes (reuse XW region)
  k_ln_bf<0><<<TOK / 4, 256, 0, stream>>>(out, n2g, n2b, XWh, XWl);
  // MLP, chunked: fc1+gelu -> H planes; fc2 + residual in-place on d_out
  for (int c = 0; c < NC; c++) {
    long r0 = (long)c * CH;
    k_mfma<1><<<dim3(CH / 128, 12), 256, 0, stream>>>(XWh + r0 * CDIM, XWl + r0 * CDIM,
        W1h, W1l, fc1b, MLPH, CDIM, nullptr, Hh, Hl, nullptr, 0);
    k_mfma<3><<<dim3(CH / 128, 3), 256, 0, stream>>>(Hh, Hl, W2h, W2l, fc2b,
        CDIM, MLPH, out, nullptr, nullptr, out, r0);
  }
}

// Round 4
// 1841.352 us; speedup vs baseline: 1.1493x; 1.1493x over previous
//
#include <hip/hip_runtime.h>
#include <math.h>

// SwinTransformerBlock: B=2,D=8,H=56,W=56,C=384, win=(2,7,7), shift=(1,3,3)
#define TOK   50176      // total tokens
#define CDIM  384
#define NTOK  98         // tokens per window
#define NHEAD 12
#define HD    32
#define MLPH  1536
#define QKVN  1152

typedef __attribute__((ext_vector_type(8))) short s16x8;
typedef __attribute__((ext_vector_type(4))) short s16x4;
typedef __attribute__((ext_vector_type(4))) float f32x4;

__device__ __forceinline__ unsigned short bf_hi(float x) {
  unsigned u = __float_as_uint(x);
  return (unsigned short)((u + 0x7fffu + ((u >> 16) & 1u)) >> 16);
}
__device__ __forceinline__ float bf_f(unsigned short h) {
  return __uint_as_float(((unsigned)h) << 16);
}

// token id (window-major) -> spatial row id (gather for LN1+shift+partition,
// scatter for window_reverse+roll; the two rolls are inverse permutations).
__device__ __forceinline__ long token_to_spatial(int t) {
  int Bidx = t / NTOK;
  int n = t % NTOK;
  int b_ = Bidx >> 8;
  int widx = Bidx & 255;
  int wd = widx >> 6, wh = (widx >> 3) & 7, ww = widx & 7;
  int nd = n / 49, nh = (n % 49) / 7, nw = n % 7;
  int dd = (wd * 2 + nd + 1) & 7;
  int hh = (wh * 7 + nh + 3) % 56;
  int wc = (ww * 7 + nw + 3) % 56;
  return ((long)(b_ * 8 + dd) * 56 + hh) * 56 + wc;
}

// ---- LayerNorm -> bf16 hi/lo planes. GATHER=1: permuted source (LN1) ----
template <int GATHER>
__global__ __launch_bounds__(256) void k_ln_bf(const float* __restrict__ x,
    const float* __restrict__ g, const float* __restrict__ bb,
    unsigned short* __restrict__ oh, unsigned short* __restrict__ ol) {
  int row = blockIdx.x * 4 + (threadIdx.x >> 6);
  int lane = threadIdx.x & 63;
  long srow = GATHER ? token_to_spatial(row) : (long)row;
  const float* src = x + srow * CDIM;
  float v[6]; float sum = 0.f, sq = 0.f;
#pragma unroll
  for (int i = 0; i < 6; i++) { float t = src[lane + i * 64]; v[i] = t; sum += t; sq += t * t; }
#pragma unroll
  for (int o = 1; o < 64; o <<= 1) { sum += __shfl_xor(sum, o); sq += __shfl_xor(sq, o); }
  float mean = sum * (1.f / 384.f);
  float rstd = rsqrtf(sq * (1.f / 384.f) - mean * mean + 1e-5f);
  long ob = (long)row * CDIM;
#pragma unroll
  for (int i = 0; i < 6; i++) {
    int c = lane + i * 64;
    float y = (v[i] - mean) * rstd * g[c] + bb[c];
    unsigned short h = bf_hi(y);
    oh[ob + c] = h; ol[ob + c] = bf_hi(y - bf_f(h));
  }
}

// ---- weight split+transpose: W fp32 [K][N] -> Th/Tl bf16 [N][K] ----
__global__ __launch_bounds__(256) void k_wsplit(const float* __restrict__ W,
    unsigned short* __restrict__ Th, unsigned short* __restrict__ Tl, int K, int N) {
  long idx = (long)blockIdx.x * 256 + threadIdx.x;
  int n = (int)(idx / K);
  int k = (int)(idx - (long)n * K);
  float v = W[(long)k * N + n];
  unsigned short h = bf_hi(v);
  Th[idx] = h; Tl[idx] = bf_hi(v - bf_f(h));
}

// ---- transpose precompute: biasT[h][m][n], maskT[w][m][n] (S^T access) ----
__global__ __launch_bounds__(256) void k_bmT(const float* __restrict__ btab,
    const float* __restrict__ mask, float* __restrict__ biasT, float* __restrict__ maskT) {
  long idx = (long)blockIdx.x * 256 + threadIdx.x;
  const long PLANE = NTOK * NTOK;
  if (idx < NHEAD * PLANE) {
    int h = (int)(idx / PLANE); int r = (int)(idx % PLANE);
    int m = r / NTOK, n = r % NTOK;
    int nd = n / 49, nh = (n % 49) / 7, nw = n % 7;
    int md = m / 49, mh = (m % 49) / 7, mw = m % 7;
    int rel = (nd - md + 1) * 169 + (nh - mh + 6) * 13 + (nw - mw + 6);
    biasT[idx] = btab[rel * NHEAD + h];
  } else {
    long j = idx - NHEAD * PLANE;
    if (j < 256 * PLANE) {
      int w = (int)(j / PLANE); int r = (int)(j % PLANE);
      int m = r / NTOK, n = r % NTOK;
      maskT[j] = mask[(long)w * PLANE + n * NTOK + m];
    }
  }
}

// ---- split-bf16 MFMA GEMM: C = A @ B^T_stored (+bias, epilogue variants)
// EPI: 1=+bias,gelu->hi/lo   2=+bias,scatter t2s,+res->f32
//      3=+bias,+res(row_base)->f32   4=+bias,(col<384?*scale:1)->hi/lo (qkv)
template <int EPI>
__global__ __launch_bounds__(256, 2) void k_mfma(
    const unsigned short* __restrict__ Ah, const unsigned short* __restrict__ Al,
    const unsigned short* __restrict__ Bh, const unsigned short* __restrict__ Bl,
    const float* __restrict__ bias, int Nn, int Kk,
    float* __restrict__ outf, unsigned short* __restrict__ outh,
    unsigned short* __restrict__ outl, const float* __restrict__ resp, long row_base) {
  __shared__ unsigned short As[2][128][32];
  __shared__ unsigned short Bs[2][128][32];
  int tid = threadIdx.x;
  int sel = tid >> 6, ln = tid & 63;
  int lr = tid & 15, lg = (tid & 63) >> 4;
  int wr = sel >> 1, wc = sel & 1;
  const unsigned short* gsrc = (sel == 0) ? Ah : (sel == 1) ? Al : (sel == 2) ? Bh : Bl;
  long grow0 = (sel < 2) ? (long)blockIdx.x * 128 : (long)blockIdx.y * 128;
  unsigned short (*ldst)[32] = (sel == 0) ? As[0] : (sel == 1) ? As[1]
                             : (sel == 2) ? Bs[0] : Bs[1];
  f32x4 acc[4][4];
#pragma unroll
  for (int i = 0; i < 4; i++)
#pragma unroll
    for (int j = 0; j < 4; j++) acc[i][j] = (f32x4){0.f, 0.f, 0.f, 0.f};

  int swz = (ln >> 1) & 3;
  int co = ((lg ^ ((lr >> 1) & 3)) << 3);

  for (int k0 = 0; k0 < Kk; k0 += 32) {
#pragma unroll
    for (int h = 0; h < 2; h++) {
      int m = ln + (h << 6);
      const unsigned short* src = gsrc + (grow0 + m) * (long)Kk + k0;
#pragma unroll
      for (int c = 0; c < 4; c++) {
        s16x8 v = *(const s16x8*)(src + (c << 3));
        *(s16x8*)&ldst[m][((c ^ swz) << 3)] = v;
      }
    }
    __syncthreads();
    s16x8 fa[2][4], fb[2][4];
#pragma unroll
    for (int i = 0; i < 4; i++) {
      int r = wr * 64 + i * 16 + lr;
      fa[0][i] = *(const s16x8*)&As[0][r][co];
      fa[1][i] = *(const s16x8*)&As[1][r][co];
      int n = wc * 64 + i * 16 + lr;
      fb[0][i] = *(const s16x8*)&Bs[0][n][co];
      fb[1][i] = *(const s16x8*)&Bs[1][n][co];
    }
#pragma unroll
    for (int i = 0; i < 4; i++)
#pragma unroll
      for (int j = 0; j < 4; j++) {
        acc[i][j] = __builtin_amdgcn_mfma_f32_16x16x32_bf16(fa[0][i], fb[0][j], acc[i][j], 0, 0, 0);
        acc[i][j] = __builtin_amdgcn_mfma_f32_16x16x32_bf16(fa[0][i], fb[1][j], acc[i][j], 0, 0, 0);
        acc[i][j] = __builtin_amdgcn_mfma_f32_16x16x32_bf16(fa[1][i], fb[0][j], acc[i][j], 0, 0, 0);
      }
    __syncthreads();
  }
  int colb = blockIdx.y * 128 + wc * 64;
  float bv[4];
#pragma unroll
  for (int j = 0; j < 4; j++) bv[j] = bias[colb + j * 16 + lr];
#pragma unroll
  for (int i = 0; i < 4; i++) {
#pragma unroll
    for (int q = 0; q < 4; q++) {
      long rl = (long)blockIdx.x * 128 + wr * 64 + i * 16 + lg * 4 + q;
      long obase;
      if constexpr (EPI == 2) obase = token_to_spatial((int)rl) * 384;
      else                    obase = (row_base + rl) * (long)Nn;
#pragma unroll
      for (int j = 0; j < 4; j++) {
        int cg = colb + j * 16 + lr;
        float v = acc[i][j][q] + bv[j];
        if constexpr (EPI == 1) {
          v = 0.5f * v * (1.f + erff(v * 0.70710678118654752f));
          unsigned short hh = bf_hi(v);
          outh[obase + cg] = hh; outl[obase + cg] = bf_hi(v - bf_f(hh));
        } else if constexpr (EPI == 4) {
          if (cg < 384) v *= 0.1767766952966369f;   // q * 32^-0.5
          unsigned short hh = bf_hi(v);
          outh[obase + cg] = hh; outl[obase + cg] = bf_hi(v - bf_f(hh));
        } else if constexpr (EPI == 2) {
          outf[obase + cg] = v + resp[obase + cg];
        } else {   // EPI 3
          outf[obase + cg] = v + resp[obase + cg];
        }
      }
    }
  }
}

// ---- MFMA flash attention: one wave per (window, head) -------------------
// S^T = K @ Q^T via mfma(K_frag, Q_frag): lane owns q-row n = nt*16+(L&15);
// D-layout puts m at position g*4+q == the B-frag placement PV needs, so P
// feeds PV directly. V^T A-frags use the same placement. Split hi/lo on both.
__global__ __launch_bounds__(256, 2) void k_attn2(
    const unsigned short* __restrict__ Qh, const unsigned short* __restrict__ Ql,
    const float* __restrict__ biasT, const float* __restrict__ maskT,
    unsigned short* __restrict__ AWh, unsigned short* __restrict__ AWl,
    int win_base) {
  const int wid = threadIdx.x >> 6;
  const int L = threadIdx.x & 63;
  const int g = L >> 4, c = L & 15;
  int wh = blockIdx.x * 4 + wid;
  int w_loc = wh / 12, h = wh - w_loc * 12;
  int w_glob = win_base + w_loc;
  long tbase = (long)w_loc * NTOK * QKVN;
  int qoff = h * HD;
  const s16x8 z8 = {0, 0, 0, 0, 0, 0, 0, 0};

  // Q fragments (B-operand): col n on (L&15), d-placement (g,e) -> g*8+e
  s16x8 qh[7], ql[7];
#pragma unroll
  for (int nt = 0; nt < 7; nt++) {
    int n = nt * 16 + c;
    if (n < NTOK) {
      long a = tbase + (long)n * QKVN + qoff + g * 8;
      qh[nt] = *(const s16x8*)(Qh + a);
      ql[nt] = *(const s16x8*)(Ql + a);
    } else { qh[nt] = z8; ql[nt] = z8; }
  }
  const float* bT = biasT + (long)h * (NTOK * NTOK);
  const float* mT = maskT + (long)(w_glob & 255) * (NTOK * NTOK);

  f32x4 o[2][7];
  float mrun[7], lrun[7];
#pragma unroll
  for (int nt = 0; nt < 7; nt++) {
    o[0][nt] = (f32x4){0.f, 0.f, 0.f, 0.f};
    o[1][nt] = (f32x4){0.f, 0.f, 0.f, 0.f};
    mrun[nt] = -1e30f; lrun[nt] = 0.f;
  }

#pragma unroll
  for (int it = 0; it < 4; it++) {
    // K fragments (A-operand of QK^T): m-token on (L&15), same d-placement
    s16x8 kh[2], kl[2];
#pragma unroll
    for (int t = 0; t < 2; t++) {
      int m = it * 32 + t * 16 + c;
      if (m < NTOK) {
        long a = tbase + (long)m * QKVN + CDIM + qoff + g * 8;
        kh[t] = *(const s16x8*)(Qh + a);
        kl[t] = *(const s16x8*)(Ql + a);
      } else { kh[t] = z8; kl[t] = z8; }
    }
    // V^T fragments (A-operand of PV): d on (L&15), m-placement e -> (e>>2)*16+g*4+(e&3)
    s16x8 vh[2], vl[2];
#pragma unroll
    for (int dt = 0; dt < 2; dt++) {
#pragma unroll
      for (int e = 0; e < 8; e++) {
        int m = it * 32 + (e >> 2) * 16 + g * 4 + (e & 3);
        unsigned short hv = 0, lv = 0;
        if (m < NTOK) {
          long a = tbase + (long)m * QKVN + 2 * CDIM + qoff + dt * 16 + c;
          hv = Qh[a]; lv = Ql[a];
        }
        vh[dt][e] = (short)hv; vl[dt][e] = (short)lv;
      }
    }
#pragma unroll
    for (int nt = 0; nt < 7; nt++) {
      f32x4 s0 = (f32x4){0.f, 0.f, 0.f, 0.f};
      f32x4 s1 = (f32x4){0.f, 0.f, 0.f, 0.f};
      s0 = __builtin_amdgcn_mfma_f32_16x16x32_bf16(kh[0], qh[nt], s0, 0, 0, 0);
      s0 = __builtin_amdgcn_mfma_f32_16x16x32_bf16(kh[0], ql[nt], s0, 0, 0, 0);
      s0 = __builtin_amdgcn_mfma_f32_16x16x32_bf16(kl[0], qh[nt], s0, 0, 0, 0);
      s1 = __builtin_amdgcn_mfma_f32_16x16x32_bf16(kh[1], qh[nt], s1, 0, 0, 0);
      s1 = __builtin_amdgcn_mfma_f32_16x16x32_bf16(kh[1], ql[nt], s1, 0, 0, 0);
      s1 = __builtin_amdgcn_mfma_f32_16x16x32_bf16(kl[1], qh[nt], s1, 0, 0, 0);
      int n = nt * 16 + c;
      float sv[8]; float pm = -1e30f;
#pragma unroll
      for (int e = 0; e < 8; e++) {
        int m = it * 32 + (e >> 2) * 16 + g * 4 + (e & 3);
        float s = (e < 4) ? s0[e & 3] : s1[e & 3];
        if (m < NTOK) {
          if (n < NTOK) s += bT[m * NTOK + n] + mT[m * NTOK + n];
        } else s = -1e30f;
        sv[e] = s; pm = fmaxf(pm, s);
      }
      pm = fmaxf(pm, __shfl_xor(pm, 16));
      pm = fmaxf(pm, __shfl_xor(pm, 32));
      float mnew = fmaxf(mrun[nt], pm);
      float alpha = __expf(mrun[nt] - mnew);
      mrun[nt] = mnew;
      float ls = 0.f;
      s16x8 ph, pl;
#pragma unroll
      for (int e = 0; e < 8; e++) {
        float p = __expf(sv[e] - mnew);
        ls += p;
        unsigned short hh = bf_hi(p);
        ph[e] = (short)hh; pl[e] = (short)bf_hi(p - bf_f(hh));
      }
      ls += __shfl_xor(ls, 16);
      ls += __shfl_xor(ls, 32);
      lrun[nt] = lrun[nt] * alpha + ls;
      o[0][nt] *= alpha;
      o[1][nt] *= alpha;
      o[0][nt] = __builtin_amdgcn_mfma_f32_16x16x32_bf16(vh[0], ph, o[0][nt], 0, 0, 0);
      o[0][nt] = __builtin_amdgcn_mfma_f32_16x16x32_bf16(vh[0], pl, o[0][nt], 0, 0, 0);
      o[0][nt] = __builtin_amdgcn_mfma_f32_16x16x32_bf16(vl[0], ph, o[0][nt], 0, 0, 0);
      o[1][nt] = __builtin_amdgcn_mfma_f32_16x16x32_bf16(vh[1], ph, o[1][nt], 0, 0, 0);
      o[1][nt] = __builtin_amdgcn_mfma_f32_16x16x32_bf16(vh[1], pl, o[1][nt], 0, 0, 0);
      o[1][nt] = __builtin_amdgcn_mfma_f32_16x16x32_bf16(vl[1], ph, o[1][nt], 0, 0, 0);
    }
  }
  // write O[n][d] -> AW planes; lane has n = nt*16+c, d = dt*16+g*4+q
#pragma unroll
  for (int nt = 0; nt < 7; nt++) {
    int n = nt * 16 + c;
    if (n >= NTOK) continue;
    float inv = 1.f / lrun[nt];
    long rowb = ((long)w_glob * NTOK + n) * CDIM + qoff;
#pragma unroll
    for (int dt = 0; dt < 2; dt++) {
      s16x4 hh, ll;
#pragma unroll
      for (int q = 0; q < 4; q++) {
        float v = o[dt][nt][q] * inv;
        unsigned short hv = bf_hi(v);
        hh[q] = (short)hv; ll[q] = (short)bf_hi(v - bf_f(hv));
      }
      *(s16x4*)(AWh + rowb + dt * 16 + g * 4) = hh;
      *(s16x4*)(AWl + rowb + dt * 16 + g * 4) = ll;
    }
  }
}

extern "C" void kernel_launch(void* const* d_in, const int* in_sizes, int n_in,
                              void* d_out, int out_size, void* d_ws, size_t ws_size,
                              hipStream_t stream) {
  const float* x     = (const float*)d_in[0];
  const float* mask  = (const float*)d_in[1];
  const float* n1g   = (const float*)d_in[2];
  const float* n1b   = (const float*)d_in[3];
  const float* qkvw  = (const float*)d_in[4];
  const float* qkvb  = (const float*)d_in[5];
  const float* btab  = (const float*)d_in[6];
  const float* projw = (const float*)d_in[7];
  const float* projb = (const float*)d_in[8];
  const float* n2g   = (const float*)d_in[9];
  const float* n2b   = (const float*)d_in[10];
  const float* fc1w  = (const float*)d_in[11];
  const float* fc1b  = (const float*)d_in[12];
  const float* fc2w  = (const float*)d_in[13];
  const float* fc2b  = (const float*)d_in[14];
  float* out = (float*)d_out;

  // ws: [XW/AW/XN2 planes 4*S1 B][chunk region: QKV planes | H planes][weights][biasT|maskT]
  const long S1 = (long)TOK * CDIM;
  const long WELEMS = 442368L + 147456L + 589824L + 589824L;
  const long BMT = (long)(NHEAD + 256) * NTOK * NTOK;   // floats
  char* b0 = (char*)d_ws;
  unsigned short* XWh = (unsigned short*)b0;
  unsigned short* XWl = XWh + S1;
  int NC = 4;
  if ((size_t)(4 * S1 + (long)(TOK / 4) * MLPH * 4 + WELEMS * 4 + BMT * 4) > ws_size) NC = 8;
  const int CH = TOK / NC;    // rows per chunk (multiple of 128 and 98)
  char* bB = b0 + 4 * S1;
  unsigned short* QKVh = (unsigned short*)bB;
  unsigned short* QKVl = QKVh + (long)CH * QKVN;
  unsigned short* Hh = (unsigned short*)bB;
  unsigned short* Hl = Hh + (long)CH * MLPH;
  unsigned short* pW = (unsigned short*)(bB + (long)CH * MLPH * 4);
  unsigned short* Wqh = pW,            *Wql = Wqh + 442368;
  unsigned short* Wph = Wql + 442368,  *Wpl = Wph + 147456;
  unsigned short* W1h = Wpl + 147456,  *W1l = W1h + 589824;
  unsigned short* W2h = W1l + 589824,  *W2l = W2h + 589824;
  float* biasT = (float*)(pW + 2 * WELEMS);
  float* maskT = biasT + (long)NHEAD * NTOK * NTOK;

  // weight split+transpose, bias/mask transpose (small, L2-resident)
  k_wsplit<<<1728, 256, 0, stream>>>(qkvw, Wqh, Wql, 384, 1152);
  k_wsplit<<<576, 256, 0, stream>>>(projw, Wph, Wpl, 384, 384);
  k_wsplit<<<2304, 256, 0, stream>>>(fc1w, W1h, W1l, 384, 1536);
  k_wsplit<<<2304, 256, 0, stream>>>(fc2w, W2h, W2l, 1536, 384);
  k_bmT<<<(int)((BMT + 255) / 256), 256, 0, stream>>>(btab, mask, biasT, maskT);
  // LN1 + shift + window-partition gather -> XW planes
  k_ln_bf<1><<<TOK / 4, 256, 0, stream>>>(x, n1g, n1b, XWh, XWl);
  // attention path, chunked: qkv GEMM (planes, q pre-scaled) -> flash attn
  for (int c = 0; c < NC; c++) {
    long r0 = (long)c * CH;
    k_mfma<4><<<dim3(CH / 128, 9), 256, 0, stream>>>(XWh + r0 * CDIM, XWl + r0 * CDIM,
        Wqh, Wql, qkvb, QKVN, CDIM, nullptr, QKVh, QKVl, nullptr, 0);
    k_attn2<<<(CH / NTOK) * 3, 256, 0, stream>>>(QKVh, QKVl, biasT, maskT,
        XWh, XWl, (int)(r0 / NTOK));
  }
  // proj + window_reverse + roll + residual(x) -> d_out (spatial order)
  k_mfma<2><<<dim3(TOK / 128, 3), 256, 0, stream>>>(XWh, XWl, Wph, Wpl, projb,
      CDIM, CDIM, out, nullptr, nullptr, x, 0);
  // LN2 -> planes (reuse XW region)
  k_ln_bf<0><<<TOK / 4, 256, 0, stream>>>(out, n2g, n2b, XWh, XWl);
  // MLP, chunked: fc1+gelu -> H planes; fc2 + residual in-place on d_out
  for (int c = 0; c < NC; c++) {
    long r0 = (long)c * CH;
    k_mfma<1><<<dim3(CH / 128, 12), 256, 0, stream>>>(XWh + r0 * CDIM, XWl + r0 * CDIM,
        W1h, W1l, fc1b, MLPH, CDIM, nullptr, Hh, Hl, nullptr, 0);
    k_mfma<3><<<dim3(CH / 128, 3), 256, 0, stream>>>(Hh, Hl, W2h, W2l, fc2b,
        CDIM, MLPH, out, nullptr, nullptr, out, r0);
  }
}

// Round 7
// 1212.567 us; speedup vs baseline: 1.7453x; 1.5186x over previous
//
#include <hip/hip_runtime.h>
#include <math.h>

// SwinTransformerBlock: B=2,D=8,H=56,W=56,C=384, win=(2,7,7), shift=(1,3,3)
#define TOK   50176      // total tokens
#define CDIM  384
#define NTOK  98         // tokens per window
#define NHEAD 12
#define HD    32
#define MLPH  1536
#define QKVN  1152

typedef __attribute__((ext_vector_type(8))) short s16x8;
typedef __attribute__((ext_vector_type(4))) short s16x4;
typedef __attribute__((ext_vector_type(4))) float f32x4;

__device__ __forceinline__ unsigned short bf_hi(float x) {
  unsigned u = __float_as_uint(x);
  return (unsigned short)((u + 0x7fffu + ((u >> 16) & 1u)) >> 16);
}
__device__ __forceinline__ float bf_f(unsigned short h) {
  return __uint_as_float(((unsigned)h) << 16);
}

// bijective XCD-aware block swizzle (m204 variant): contiguous logical range per XCD
__device__ __forceinline__ int swz8(int b, int nwg) {
  int q = nwg >> 3, r = nwg & 7;
  int x = b & 7, p = b >> 3;
  return (x < r ? x * (q + 1) : r * (q + 1) + (x - r) * q) + p;
}

// token id (window-major) -> spatial row id (gather for LN1+shift+partition,
// scatter for window_reverse+roll; the two rolls are inverse permutations).
__device__ __forceinline__ long token_to_spatial(int t) {
  int Bidx = t / NTOK;
  int n = t % NTOK;
  int b_ = Bidx >> 8;
  int widx = Bidx & 255;
  int wd = widx >> 6, wh = (widx >> 3) & 7, ww = widx & 7;
  int nd = n / 49, nh = (n % 49) / 7, nw = n % 7;
  int dd = (wd * 2 + nd + 1) & 7;
  int hh = (wh * 7 + nh + 3) % 56;
  int wc = (ww * 7 + nw + 3) % 56;
  return ((long)(b_ * 8 + dd) * 56 + hh) * 56 + wc;
}

// ---- LayerNorm -> bf16 planes. GATHER: permuted src. WLO: write lo plane ----
template <int GATHER, int WLO>
__global__ __launch_bounds__(256) void k_ln_bf(const float* __restrict__ x,
    const float* __restrict__ g, const float* __restrict__ bb,
    unsigned short* __restrict__ oh, unsigned short* __restrict__ ol) {
  int row = blockIdx.x * 4 + (threadIdx.x >> 6);
  int lane = threadIdx.x & 63;
  long srow = GATHER ? token_to_spatial(row) : (long)row;
  const float* src = x + srow * CDIM;
  float v[6]; float sum = 0.f, sq = 0.f;
#pragma unroll
  for (int i = 0; i < 6; i++) { float t = src[lane + i * 64]; v[i] = t; sum += t; sq += t * t; }
#pragma unroll
  for (int o = 1; o < 64; o <<= 1) { sum += __shfl_xor(sum, o); sq += __shfl_xor(sq, o); }
  float mean = sum * (1.f / 384.f);
  float rstd = rsqrtf(sq * (1.f / 384.f) - mean * mean + 1e-5f);
  long ob = (long)row * CDIM;
#pragma unroll
  for (int i = 0; i < 6; i++) {
    int c = lane + i * 64;
    float y = (v[i] - mean) * rstd * g[c] + bb[c];
    unsigned short h = bf_hi(y);
    oh[ob + c] = h;
    if constexpr (WLO) ol[ob + c] = bf_hi(y - bf_f(h));
  }
}

// ---- weight split+transpose: W fp32 [K][N] -> Th/Tl bf16 [N][K] ----
__global__ __launch_bounds__(256) void k_wsplit(const float* __restrict__ W,
    unsigned short* __restrict__ Th, unsigned short* __restrict__ Tl, int K, int N) {
  long idx = (long)blockIdx.x * 256 + threadIdx.x;
  int n = (int)(idx / K);
  int k = (int)(idx - (long)n * K);
  float v = W[(long)k * N + n];
  unsigned short h = bf_hi(v);
  Th[idx] = h; Tl[idx] = bf_hi(v - bf_f(h));
}

// ---- transpose precompute: biasT[h][m][n], maskT[w][m][n] (S^T access) ----
__global__ __launch_bounds__(256) void k_bmT(const float* __restrict__ btab,
    const float* __restrict__ mask, float* __restrict__ biasT, float* __restrict__ maskT) {
  long idx = (long)blockIdx.x * 256 + threadIdx.x;
  const long PLANE = NTOK * NTOK;
  if (idx < NHEAD * PLANE) {
    int h = (int)(idx / PLANE); int r = (int)(idx % PLANE);
    int m = r / NTOK, n = r % NTOK;
    int nd = n / 49, nh = (n % 49) / 7, nw = n % 7;
    int md = m / 49, mh = (m % 49) / 7, mw = m % 7;
    int rel = (nd - md + 1) * 169 + (nh - mh + 6) * 13 + (nw - mw + 6);
    biasT[idx] = btab[rel * NHEAD + h];
  } else {
    long j = idx - NHEAD * PLANE;
    if (j < 256 * PLANE) {
      int w = (int)(j / PLANE); int r = (int)(j % PLANE);
      int m = r / NTOK, n = r % NTOK;
      maskT[j] = mask[(long)w * PLANE + n * NTOK + m];
    }
  }
}

// ---- split-bf16 MFMA GEMM: C = A @ B^T_stored (+bias, epilogue variants)
// SPLITA=1: A hi/lo, 3 passes (AhBh+AhBl+AlBh). SPLITA=0: A hi only, 2 passes.
// 1-D grid, col-tile fastest (A-panel sharing blocks consecutive) + XCD swizzle.
// EPI: 2=+bias,scatter t2s,+res->f32   3=+bias,+res(row_base)->f32
//      4=+bias,(col<384?*scale:1)->hi/lo planes (qkv)   5=+bias,gelu->hi plane
template <int EPI, int SPLITA>
__global__ __launch_bounds__(256, 2) void k_mfma(
    const unsigned short* __restrict__ Ah, const unsigned short* __restrict__ Al,
    const unsigned short* __restrict__ Bh, const unsigned short* __restrict__ Bl,
    const float* __restrict__ bias, int Nn, int Kk,
    float* __restrict__ outf, unsigned short* __restrict__ outh,
    unsigned short* __restrict__ outl, const float* __restrict__ resp, long row_base) {
  __shared__ unsigned short As[SPLITA + 1][128][32];
  __shared__ unsigned short Bs[2][128][32];
  int tid = threadIdx.x;
  int sel = tid >> 6, ln = tid & 63;
  int lr = tid & 15, lg = (tid & 63) >> 4;
  int wr = sel >> 1, wc = sel & 1;
  int NT = Nn >> 7;
  int lbid = swz8(blockIdx.x, gridDim.x);
  int bx = lbid % NT, by = lbid / NT;
  long rowB = (long)by * 128;
  int  colB = bx * 128;

  const unsigned short* gsrc;
  unsigned short (*ldst)[32];
  long grow0; int row_s, nrow;
  if constexpr (SPLITA) {
    gsrc = (sel == 0) ? Ah : (sel == 1) ? Al : (sel == 2) ? Bh : Bl;
    ldst = (sel == 0) ? As[0] : (sel == 1) ? As[1] : (sel == 2) ? Bs[0] : Bs[1];
    grow0 = (sel < 2) ? rowB : (long)colB;
    row_s = ln; nrow = 2;
  } else {
    gsrc = (sel < 2) ? Ah : (sel == 2) ? Bh : Bl;
    ldst = (sel < 2) ? As[0] : (sel == 2) ? Bs[0] : Bs[1];
    grow0 = (sel < 2) ? rowB : (long)colB;
    row_s = (sel == 1) ? 64 + ln : ln;
    nrow = (sel < 2) ? 1 : 2;
  }
  f32x4 acc[4][4];
#pragma unroll
  for (int i = 0; i < 4; i++)
#pragma unroll
    for (int j = 0; j < 4; j++) acc[i][j] = (f32x4){0.f, 0.f, 0.f, 0.f};

  int swz = (ln >> 1) & 3;                 // staging k-chunk swizzle
  int co = ((lg ^ ((lr >> 1) & 3)) << 3);  // matching fragment-read chunk

  for (int k0 = 0; k0 < Kk; k0 += 32) {
    for (int h = 0; h < nrow; h++) {
      int m = row_s + (h << 6);
      const unsigned short* src = gsrc + (grow0 + m) * (long)Kk + k0;
#pragma unroll
      for (int c = 0; c < 4; c++) {
        s16x8 v = *(const s16x8*)(src + (c << 3));
        *(s16x8*)&ldst[m][((c ^ swz) << 3)] = v;
      }
    }
    __syncthreads();
    s16x8 fah[4], fal[4], fbh[4], fbl[4];
#pragma unroll
    for (int i = 0; i < 4; i++) {
      int r = wr * 64 + i * 16 + lr;
      fah[i] = *(const s16x8*)&As[0][r][co];
      if constexpr (SPLITA) fal[i] = *(const s16x8*)&As[1][r][co];
      int n = wc * 64 + i * 16 + lr;
      fbh[i] = *(const s16x8*)&Bs[0][n][co];
      fbl[i] = *(const s16x8*)&Bs[1][n][co];
    }
#pragma unroll
    for (int i = 0; i < 4; i++)
#pragma unroll
      for (int j = 0; j < 4; j++) {
        acc[i][j] = __builtin_amdgcn_mfma_f32_16x16x32_bf16(fah[i], fbh[j], acc[i][j], 0, 0, 0);
        acc[i][j] = __builtin_amdgcn_mfma_f32_16x16x32_bf16(fah[i], fbl[j], acc[i][j], 0, 0, 0);
        if constexpr (SPLITA)
          acc[i][j] = __builtin_amdgcn_mfma_f32_16x16x32_bf16(fal[i], fbh[j], acc[i][j], 0, 0, 0);
      }
    __syncthreads();
  }
  // epilogue: D row = rowB+wr*64+i*16+lg*4+q, col = colB+wc*64+j*16+lr
  int colb = colB + wc * 64;
  float bv[4];
#pragma unroll
  for (int j = 0; j < 4; j++) bv[j] = bias[colb + j * 16 + lr];
#pragma unroll
  for (int i = 0; i < 4; i++) {
#pragma unroll
    for (int q = 0; q < 4; q++) {
      long rl = rowB + wr * 64 + i * 16 + lg * 4 + q;
      long obase;
      if constexpr (EPI == 2) obase = token_to_spatial((int)rl) * 384;
      else                    obase = (row_base + rl) * (long)Nn;
#pragma unroll
      for (int j = 0; j < 4; j++) {
        int cg = colb + j * 16 + lr;
        float v = acc[i][j][q] + bv[j];
        if constexpr (EPI == 4) {
          if (cg < 384) v *= 0.1767766952966369f;   // q * 32^-0.5
          unsigned short hh = bf_hi(v);
          outh[obase + cg] = hh; outl[obase + cg] = bf_hi(v - bf_f(hh));
        } else if constexpr (EPI == 5) {
          v = 0.5f * v * (1.f + erff(v * 0.70710678118654752f));
          outh[obase + cg] = bf_hi(v);
        } else {   // EPI 2 or 3: +residual, fp32 out
          outf[obase + cg] = v + resp[obase + cg];
        }
      }
    }
  }
}

// ---- MFMA flash attention: one wave per (window, head) -------------------
// S^T = K @ Q^T via mfma(K_frag, Q_frag): lane owns q-row n = nt*16+(L&15);
// D-layout puts m at position g*4+q == the B-frag placement PV needs, so P
// feeds PV directly. V^T A-frags use the same placement. Split hi/lo on both.
__global__ __launch_bounds__(256, 2) void k_attn2(
    const unsigned short* __restrict__ Qh, const unsigned short* __restrict__ Ql,
    const float* __restrict__ biasT, const float* __restrict__ maskT,
    unsigned short* __restrict__ AWh, unsigned short* __restrict__ AWl,
    int win_base) {
  const int wid = threadIdx.x >> 6;
  const int L = threadIdx.x & 63;
  const int g = L >> 4, c = L & 15;
  int wh = blockIdx.x * 4 + wid;
  int w_loc = wh / 12, h = wh - w_loc * 12;
  int w_glob = win_base + w_loc;
  long tbase = (long)w_loc * NTOK * QKVN;
  int qoff = h * HD;
  const s16x8 z8 = {0, 0, 0, 0, 0, 0, 0, 0};

  s16x8 qh[7], ql[7];
#pragma unroll
  for (int nt = 0; nt < 7; nt++) {
    int n = nt * 16 + c;
    if (n < NTOK) {
      long a = tbase + (long)n * QKVN + qoff + g * 8;
      qh[nt] = *(const s16x8*)(Qh + a);
      ql[nt] = *(const s16x8*)(Ql + a);
    } else { qh[nt] = z8; ql[nt] = z8; }
  }
  const float* bT = biasT + (long)h * (NTOK * NTOK);
  const float* mT = maskT + (long)(w_glob & 255) * (NTOK * NTOK);

  f32x4 o[2][7];
  float mrun[7], lrun[7];
#pragma unroll
  for (int nt = 0; nt < 7; nt++) {
    o[0][nt] = (f32x4){0.f, 0.f, 0.f, 0.f};
    o[1][nt] = (f32x4){0.f, 0.f, 0.f, 0.f};
    mrun[nt] = -1e30f; lrun[nt] = 0.f;
  }

#pragma unroll
  for (int it = 0; it < 4; it++) {
    s16x8 kh[2], kl[2];
#pragma unroll
    for (int t = 0; t < 2; t++) {
      int m = it * 32 + t * 16 + c;
      if (m < NTOK) {
        long a = tbase + (long)m * QKVN + CDIM + qoff + g * 8;
        kh[t] = *(const s16x8*)(Qh + a);
        kl[t] = *(const s16x8*)(Ql + a);
      } else { kh[t] = z8; kl[t] = z8; }
    }
    s16x8 vh[2], vl[2];
#pragma unroll
    for (int dt = 0; dt < 2; dt++) {
#pragma unroll
      for (int e = 0; e < 8; e++) {
        int m = it * 32 + (e >> 2) * 16 + g * 4 + (e & 3);
        unsigned short hv = 0, lv = 0;
        if (m < NTOK) {
          long a = tbase + (long)m * QKVN + 2 * CDIM + qoff + dt * 16 + c;
          hv = Qh[a]; lv = Ql[a];
        }
        vh[dt][e] = (short)hv; vl[dt][e] = (short)lv;
      }
    }
#pragma unroll
    for (int nt = 0; nt < 7; nt++) {
      f32x4 s0 = (f32x4){0.f, 0.f, 0.f, 0.f};
      f32x4 s1 = (f32x4){0.f, 0.f, 0.f, 0.f};
      s0 = __builtin_amdgcn_mfma_f32_16x16x32_bf16(kh[0], qh[nt], s0, 0, 0, 0);
      s0 = __builtin_amdgcn_mfma_f32_16x16x32_bf16(kh[0], ql[nt], s0, 0, 0, 0);
      s0 = __builtin_amdgcn_mfma_f32_16x16x32_bf16(kl[0], qh[nt], s0, 0, 0, 0);
      s1 = __builtin_amdgcn_mfma_f32_16x16x32_bf16(kh[1], qh[nt], s1, 0, 0, 0);
      s1 = __builtin_amdgcn_mfma_f32_16x16x32_bf16(kh[1], ql[nt], s1, 0, 0, 0);
      s1 = __builtin_amdgcn_mfma_f32_16x16x32_bf16(kl[1], qh[nt], s1, 0, 0, 0);
      int n = nt * 16 + c;
      float sv[8]; float pm = -1e30f;
#pragma unroll
      for (int e = 0; e < 8; e++) {
        int m = it * 32 + (e >> 2) * 16 + g * 4 + (e & 3);
        float s = (e < 4) ? s0[e & 3] : s1[e & 3];
        if (m < NTOK) {
          if (n < NTOK) s += bT[m * NTOK + n] + mT[m * NTOK + n];
        } else s = -1e30f;
        sv[e] = s; pm = fmaxf(pm, s);
      }
      pm = fmaxf(pm, __shfl_xor(pm, 16));
      pm = fmaxf(pm, __shfl_xor(pm, 32));
      float mnew = fmaxf(mrun[nt], pm);
      float alpha = __expf(mrun[nt] - mnew);
      mrun[nt] = mnew;
      float ls = 0.f;
      s16x8 ph, pl;
#pragma unroll
      for (int e = 0; e < 8; e++) {
        float p = __expf(sv[e] - mnew);
        ls += p;
        unsigned short hh = bf_hi(p);
        ph[e] = (short)hh; pl[e] = (short)bf_hi(p - bf_f(hh));
      }
      ls += __shfl_xor(ls, 16);
      ls += __shfl_xor(ls, 32);
      lrun[nt] = lrun[nt] * alpha + ls;
      o[0][nt] *= alpha;
      o[1][nt] *= alpha;
      o[0][nt] = __builtin_amdgcn_mfma_f32_16x16x32_bf16(vh[0], ph, o[0][nt], 0, 0, 0);
      o[0][nt] = __builtin_amdgcn_mfma_f32_16x16x32_bf16(vh[0], pl, o[0][nt], 0, 0, 0);
      o[0][nt] = __builtin_amdgcn_mfma_f32_16x16x32_bf16(vl[0], ph, o[0][nt], 0, 0, 0);
      o[1][nt] = __builtin_amdgcn_mfma_f32_16x16x32_bf16(vh[1], ph, o[1][nt], 0, 0, 0);
      o[1][nt] = __builtin_amdgcn_mfma_f32_16x16x32_bf16(vh[1], pl, o[1][nt], 0, 0, 0);
      o[1][nt] = __builtin_amdgcn_mfma_f32_16x16x32_bf16(vl[1], ph, o[1][nt], 0, 0, 0);
    }
  }
#pragma unroll
  for (int nt = 0; nt < 7; nt++) {
    int n = nt * 16 + c;
    if (n >= NTOK) continue;
    float inv = 1.f / lrun[nt];
    long rowb = ((long)w_glob * NTOK + n) * CDIM + qoff;
#pragma unroll
    for (int dt = 0; dt < 2; dt++) {
      s16x4 hh, ll;
#pragma unroll
      for (int q = 0; q < 4; q++) {
        float v = o[dt][nt][q] * inv;
        unsigned short hv = bf_hi(v);
        hh[q] = (short)hv; ll[q] = (short)bf_hi(v - bf_f(hv));
      }
      *(s16x4*)(AWh + rowb + dt * 16 + g * 4) = hh;
      *(s16x4*)(AWl + rowb + dt * 16 + g * 4) = ll;
    }
  }
}

extern "C" void kernel_launch(void* const* d_in, const int* in_sizes, int n_in,
                              void* d_out, int out_size, void* d_ws, size_t ws_size,
                              hipStream_t stream) {
  const float* x     = (const float*)d_in[0];
  const float* mask  = (const float*)d_in[1];
  const float* n1g   = (const float*)d_in[2];
  const float* n1b   = (const float*)d_in[3];
  const float* qkvw  = (const float*)d_in[4];
  const float* qkvb  = (const float*)d_in[5];
  const float* btab  = (const float*)d_in[6];
  const float* projw = (const float*)d_in[7];
  const float* projb = (const float*)d_in[8];
  const float* n2g   = (const float*)d_in[9];
  const float* n2b   = (const float*)d_in[10];
  const float* fc1w  = (const float*)d_in[11];
  const float* fc1b  = (const float*)d_in[12];
  const float* fc2w  = (const float*)d_in[13];
  const float* fc2b  = (const float*)d_in[14];
  float* out = (float*)d_out;

  // ws: [XWh|XWl planes][shared region: QKV chunk planes / H single plane][weights][biasT|maskT]
  const long S1 = (long)TOK * CDIM;
  const long WELEMS = 442368L + 147456L + 589824L + 589824L;
  const long BMT = (long)(NHEAD + 256) * NTOK * NTOK;   // floats
  size_t base_b = 4ull * S1 + (size_t)WELEMS * 4 + (size_t)BMT * 4;
  // candidate region sizes (bytes)
  size_t regA = (size_t)TOK * MLPH * 2;            // NCM=1 H full (>= NC=2 qkv chunk)
  size_t regB = (size_t)(TOK / 2) * MLPH * 2;      // NCM=2 (>= NC=4 qkv chunk)
  size_t regC = (size_t)(TOK / 4) * QKVN * 4;      // NCM=4, NC=4 (qkv chunk dominates)
  size_t regD = (size_t)(TOK / 8) * QKVN * 4;      // NCM=8, NC=8
  int NC, NCM; size_t region;
  if (base_b + regA <= ws_size)      { NCM = 1; NC = 2; region = regA; }
  else if (base_b + regB <= ws_size) { NCM = 2; NC = 4; region = regB; }
  else if (base_b + regC <= ws_size) { NCM = 4; NC = 4; region = regC; }
  else                               { NCM = 8; NC = 8; region = regD; }
  const int CH  = TOK / NC;    // qkv/attn chunk rows (mult of 128 & 98)
  const int CHM = TOK / NCM;   // MLP chunk rows

  char* b0 = (char*)d_ws;
  unsigned short* XWh = (unsigned short*)b0;
  unsigned short* XWl = XWh + S1;
  char* bB = b0 + 4 * S1;
  unsigned short* QKVh = (unsigned short*)bB;
  unsigned short* QKVl = QKVh + (long)CH * QKVN;
  unsigned short* Hh = (unsigned short*)bB;
  unsigned short* pW = (unsigned short*)(bB + region);
  unsigned short* Wqh = pW,            *Wql = Wqh + 442368;
  unsigned short* Wph = Wql + 442368,  *Wpl = Wph + 147456;
  unsigned short* W1h = Wpl + 147456,  *W1l = W1h + 589824;
  unsigned short* W2h = W1l + 589824,  *W2l = W2h + 589824;
  float* biasT = (float*)(pW + 2 * WELEMS);
  float* maskT = biasT + (long)NHEAD * NTOK * NTOK;

  // weight split+transpose, bias/mask transpose (small, L2-resident)
  k_wsplit<<<1728, 256, 0, stream>>>(qkvw, Wqh, Wql, 384, 1152);
  k_wsplit<<<576, 256, 0, stream>>>(projw, Wph, Wpl, 384, 384);
  k_wsplit<<<2304, 256, 0, stream>>>(fc1w, W1h, W1l, 384, 1536);
  k_wsplit<<<2304, 256, 0, stream>>>(fc2w, W2h, W2l, 1536, 384);
  k_bmT<<<(int)((BMT + 255) / 256), 256, 0, stream>>>(btab, mask, biasT, maskT);
  // LN1 + shift + window-partition gather -> XW hi/lo planes
  k_ln_bf<1, 1><<<TOK / 4, 256, 0, stream>>>(x, n1g, n1b, XWh, XWl);
  // attention path, chunked: qkv GEMM (planes, q pre-scaled) -> flash attn
  for (int c = 0; c < NC; c++) {
    long r0 = (long)c * CH;
    k_mfma<4, 1><<<9 * (CH / 128), 256, 0, stream>>>(XWh + r0 * CDIM, XWl + r0 * CDIM,
        Wqh, Wql, qkvb, QKVN, CDIM, nullptr, QKVh, QKVl, nullptr, 0);
    k_attn2<<<(CH / NTOK) * 3, 256, 0, stream>>>(QKVh, QKVl, biasT, maskT,
        XWh, XWl, (int)(r0 / NTOK));
  }
  // proj + window_reverse + roll + residual(x) -> d_out (spatial order)
  k_mfma<2, 1><<<3 * (TOK / 128), 256, 0, stream>>>(XWh, XWl, Wph, Wpl, projb,
      CDIM, CDIM, out, nullptr, nullptr, x, 0);
  // LN2 -> XWh single plane (fc1 is 2-pass, lo unused)
  k_ln_bf<0, 0><<<TOK / 4, 256, 0, stream>>>(out, n2g, n2b, XWh, nullptr);
  // MLP: fc1+gelu -> H single plane; fc2 + residual in-place on d_out
  for (int c = 0; c < NCM; c++) {
    long r0 = (long)c * CHM;
    k_mfma<5, 0><<<12 * (CHM / 128), 256, 0, stream>>>(XWh + r0 * CDIM, nullptr,
        W1h, W1l, fc1b, MLPH, CDIM, nullptr, Hh, nullptr, nullptr, 0);
    k_mfma<3, 0><<<3 * (CHM / 128), 256, 0, stream>>>(Hh, nullptr, W2h, W2l, fc2b,
        CDIM, MLPH, out, nullptr, nullptr, out, r0);
  }
}

// Round 9
// 953.562 us; speedup vs baseline: 2.2193x; 1.2716x over previous
//
#include <hip/hip_runtime.h>
#include <math.h>

// SwinTransformerBlock: B=2,D=8,H=56,W=56,C=384, win=(2,7,7), shift=(1,3,3)
#define TOK   50176      // total tokens
#define CDIM  384
#define NTOK  98         // tokens per window
#define NHEAD 12
#define HD    32
#define MLPH  1536
#define QKVN  1152

typedef __attribute__((ext_vector_type(8))) short s16x8;
typedef __attribute__((ext_vector_type(4))) short s16x4;
typedef __attribute__((ext_vector_type(4))) float f32x4;

__device__ __forceinline__ unsigned short bf_hi(float x) {
  unsigned u = __float_as_uint(x);
  return (unsigned short)((u + 0x7fffu + ((u >> 16) & 1u)) >> 16);
}
__device__ __forceinline__ float bf_f(unsigned short h) {
  return __uint_as_float(((unsigned)h) << 16);
}

// async global->LDS DMA, 16B per lane (dst = uniform base + lane*16)
__device__ __forceinline__ void gld16(const unsigned short* g, unsigned short* l) {
  __builtin_amdgcn_global_load_lds(
      (const __attribute__((address_space(1))) unsigned int*)g,
      (__attribute__((address_space(3))) unsigned int*)l, 16, 0, 0);
}

// bijective XCD-aware block swizzle (m204 variant)
__device__ __forceinline__ int swz8(int b, int nwg) {
  int q = nwg >> 3, r = nwg & 7;
  int x = b & 7, p = b >> 3;
  return (x < r ? x * (q + 1) : r * (q + 1) + (x - r) * q) + p;
}

// token id (window-major) -> spatial row id (gather for LN1+shift+partition,
// scatter for window_reverse+roll; the two rolls are inverse permutations).
__device__ __forceinline__ long token_to_spatial(int t) {
  int Bidx = t / NTOK;
  int n = t % NTOK;
  int b_ = Bidx >> 8;
  int widx = Bidx & 255;
  int wd = widx >> 6, wh = (widx >> 3) & 7, ww = widx & 7;
  int nd = n / 49, nh = (n % 49) / 7, nw = n % 7;
  int dd = (wd * 2 + nd + 1) & 7;
  int hh = (wh * 7 + nh + 3) % 56;
  int wc = (ww * 7 + nw + 3) % 56;
  return ((long)(b_ * 8 + dd) * 56 + hh) * 56 + wc;
}

// ---- LayerNorm -> bf16 planes. GATHER: permuted src. WLO: write lo plane ----
template <int GATHER, int WLO>
__global__ __launch_bounds__(256) void k_ln_bf(const float* __restrict__ x,
    const float* __restrict__ g, const float* __restrict__ bb,
    unsigned short* __restrict__ oh, unsigned short* __restrict__ ol) {
  int row = blockIdx.x * 4 + (threadIdx.x >> 6);
  int lane = threadIdx.x & 63;
  long srow = GATHER ? token_to_spatial(row) : (long)row;
  const float* src = x + srow * CDIM;
  float v[6]; float sum = 0.f, sq = 0.f;
#pragma unroll
  for (int i = 0; i < 6; i++) { float t = src[lane + i * 64]; v[i] = t; sum += t; sq += t * t; }
#pragma unroll
  for (int o = 1; o < 64; o <<= 1) { sum += __shfl_xor(sum, o); sq += __shfl_xor(sq, o); }
  float mean = sum * (1.f / 384.f);
  float rstd = rsqrtf(sq * (1.f / 384.f) - mean * mean + 1e-5f);
  long ob = (long)row * CDIM;
#pragma unroll
  for (int i = 0; i < 6; i++) {
    int c = lane + i * 64;
    float y = (v[i] - mean) * rstd * g[c] + bb[c];
    unsigned short h = bf_hi(y);
    oh[ob + c] = h;
    if constexpr (WLO) ol[ob + c] = bf_hi(y - bf_f(h));
  }
}

// ---- merged weight split+transpose for all 4 weights (one launch) ----
__global__ __launch_bounds__(256) void k_prep(
    const float* __restrict__ qkvw, const float* __restrict__ projw,
    const float* __restrict__ fc1w, const float* __restrict__ fc2w,
    unsigned short* __restrict__ Wqh, unsigned short* __restrict__ Wql,
    unsigned short* __restrict__ Wph, unsigned short* __restrict__ Wpl,
    unsigned short* __restrict__ W1h, unsigned short* __restrict__ W1l,
    unsigned short* __restrict__ W2h, unsigned short* __restrict__ W2l) {
  long idx = (long)blockIdx.x * 256 + threadIdx.x;
  const float* W; unsigned short *Th, *Tl; int K, N; long off;
  if (idx < 442368L)              { W = qkvw; Th = Wqh; Tl = Wql; K = 384;  N = 1152; off = idx; }
  else if (idx < 589824L)         { W = projw; Th = Wph; Tl = Wpl; K = 384;  N = 384;  off = idx - 442368L; }
  else if (idx < 1179648L)        { W = fc1w; Th = W1h; Tl = W1l; K = 384;  N = 1536; off = idx - 589824L; }
  else                            { W = fc2w; Th = W2h; Tl = W2l; K = 1536; N = 384;  off = idx - 1179648L; }
  int n = (int)(off / K);
  int k = (int)(off - (long)n * K);
  float v = W[(long)k * N + n];
  unsigned short h = bf_hi(v);
  Th[off] = h; Tl[off] = bf_hi(v - bf_f(h));
}

// ---- transpose precompute: biasT[h][m][n], maskT[w][m][n] (S^T access) ----
__global__ __launch_bounds__(256) void k_bmT(const float* __restrict__ btab,
    const float* __restrict__ mask, float* __restrict__ biasT, float* __restrict__ maskT) {
  long idx = (long)blockIdx.x * 256 + threadIdx.x;
  const long PLANE = NTOK * NTOK;
  if (idx < NHEAD * PLANE) {
    int h = (int)(idx / PLANE); int r = (int)(idx % PLANE);
    int m = r / NTOK, n = r % NTOK;
    int nd = n / 49, nh = (n % 49) / 7, nw = n % 7;
    int md = m / 49, mh = (m % 49) / 7, mw = m % 7;
    int rel = (nd - md + 1) * 169 + (nh - mh + 6) * 13 + (nw - mw + 6);
    biasT[idx] = btab[rel * NHEAD + h];
  } else {
    long j = idx - NHEAD * PLANE;
    if (j < 256 * PLANE) {
      int w = (int)(j / PLANE); int r = (int)(j % PLANE);
      int m = r / NTOK, n = r % NTOK;
      maskT[j] = mask[(long)w * PLANE + n * NTOK + m];
    }
  }
}

// ---- split-bf16 MFMA GEMM: C = A @ B^T_stored (+bias, epilogue variants)
// SPLITA=1: A hi/lo, 3 passes. SPLITA=0: A hi only, 2 passes.
// Staging via global_load_lds (DMA): linear LDS dest, chunk-swizzle applied on
// the per-lane GLOBAL source address; fragment-read swizzle unchanged (rule #21).
// EPI: 2=+bias,scatter t2s,+res->f32   3=+bias,+res(row_base)->f32
//      4=+bias,(col<384?*scale:1)->hi/lo planes (qkv)   5=+bias,gelu->hi plane
template <int EPI, int SPLITA>
__global__ __launch_bounds__(256, 2) void k_mfma(
    const unsigned short* __restrict__ Ah, const unsigned short* __restrict__ Al,
    const unsigned short* __restrict__ Bh, const unsigned short* __restrict__ Bl,
    const float* __restrict__ bias, int Nn, int Kk,
    float* __restrict__ outf, unsigned short* __restrict__ outh,
    unsigned short* __restrict__ outl, const float* __restrict__ resp, long row_base) {
  __shared__ unsigned short As[SPLITA + 1][128][32];
  __shared__ unsigned short Bs[2][128][32];
  int tid = threadIdx.x;
  int sel = tid >> 6, ln = tid & 63;
  int lr = tid & 15, lg = (tid & 63) >> 4;
  int wr = sel >> 1, wc = sel & 1;
  int NT = Nn >> 7;
  int lbid = swz8(blockIdx.x, gridDim.x);
  int bx = lbid % NT, by = lbid / NT;
  long rowB = (long)by * 128;
  int  colB = bx * 128;

  // per-wave staging assignment: tile base, source, rows [r0, r0+16*nrh)
  const unsigned short* gsrc;
  unsigned short (*ltile)[32];
  long grow0; int r0, nrh;
  if constexpr (SPLITA) {
    gsrc = (sel == 0) ? Ah : (sel == 1) ? Al : (sel == 2) ? Bh : Bl;
    ltile = (sel == 0) ? As[0] : (sel == 1) ? As[1] : (sel == 2) ? Bs[0] : Bs[1];
    grow0 = (sel < 2) ? rowB : (long)colB;
    r0 = 0; nrh = 8;
  } else {
    gsrc = (sel < 2) ? Ah : (sel == 2) ? Bh : Bl;
    ltile = (sel < 2) ? As[0] : (sel == 2) ? Bs[0] : Bs[1];
    grow0 = (sel < 2) ? rowB : (long)colB;
    r0 = (sel == 1) ? 64 : 0;
    nrh = (sel < 2) ? 4 : 8;
  }
  // per-lane source address: row mb, source chunk sc = lane_chunk ^ swz(mb);
  // swz(m) = (m>>1)&3 is invariant under m += 16*h, so sc is h-invariant.
  int lrow = ln >> 2, lch = ln & 3;
  int mb = r0 + lrow;
  int sc = lch ^ ((mb >> 1) & 3);
  const unsigned short* gl = gsrc + (grow0 + mb) * (long)Kk + sc * 8;

  f32x4 acc[4][4];
#pragma unroll
  for (int i = 0; i < 4; i++)
#pragma unroll
    for (int j = 0; j < 4; j++) acc[i][j] = (f32x4){0.f, 0.f, 0.f, 0.f};

  int co = ((lg ^ ((lr >> 1) & 3)) << 3);  // fragment-read swizzled k-chunk

  for (int k0 = 0; k0 < Kk; k0 += 32) {
    for (int h = 0; h < nrh; h++)
      gld16(gl + k0 + (long)h * 16 * Kk, &ltile[r0 + h * 16][0]);
    __syncthreads();   // drains vmcnt -> tiles resident
    s16x8 fah[4], fal[4], fbh[4], fbl[4];
#pragma unroll
    for (int i = 0; i < 4; i++) {
      int r = wr * 64 + i * 16 + lr;
      fah[i] = *(const s16x8*)&As[0][r][co];
      if constexpr (SPLITA) fal[i] = *(const s16x8*)&As[1][r][co];
      int n = wc * 64 + i * 16 + lr;
      fbh[i] = *(const s16x8*)&Bs[0][n][co];
      fbl[i] = *(const s16x8*)&Bs[1][n][co];
    }
#pragma unroll
    for (int i = 0; i < 4; i++)
#pragma unroll
      for (int j = 0; j < 4; j++) {
        acc[i][j] = __builtin_amdgcn_mfma_f32_16x16x32_bf16(fah[i], fbh[j], acc[i][j], 0, 0, 0);
        acc[i][j] = __builtin_amdgcn_mfma_f32_16x16x32_bf16(fah[i], fbl[j], acc[i][j], 0, 0, 0);
        if constexpr (SPLITA)
          acc[i][j] = __builtin_amdgcn_mfma_f32_16x16x32_bf16(fal[i], fbh[j], acc[i][j], 0, 0, 0);
      }
    __syncthreads();   // all reads done before next k-step overwrites
  }
  // epilogue: D row = rowB+wr*64+i*16+lg*4+q, col = colB+wc*64+j*16+lr
  int colb = colB + wc * 64;
  float bv[4];
#pragma unroll
  for (int j = 0; j < 4; j++) bv[j] = bias[colb + j * 16 + lr];
#pragma unroll
  for (int i = 0; i < 4; i++) {
#pragma unroll
    for (int q = 0; q < 4; q++) {
      long rl = rowB + wr * 64 + i * 16 + lg * 4 + q;
      long obase;
      if constexpr (EPI == 2) obase = token_to_spatial((int)rl) * 384;
      else                    obase = (row_base + rl) * (long)Nn;
#pragma unroll
      for (int j = 0; j < 4; j++) {
        int cg = colb + j * 16 + lr;
        float v = acc[i][j][q] + bv[j];
        if constexpr (EPI == 4) {
          if (cg < 384) v *= 0.1767766952966369f;   // q * 32^-0.5
          unsigned short hh = bf_hi(v);
          outh[obase + cg] = hh; outl[obase + cg] = bf_hi(v - bf_f(hh));
        } else if constexpr (EPI == 5) {
          v = 0.5f * v * (1.f + erff(v * 0.70710678118654752f));
          outh[obase + cg] = bf_hi(v);
        } else {   // EPI 2 or 3: +residual, fp32 out
          outf[obase + cg] = v + resp[obase + cg];
        }
      }
    }
  }
}

// ---- MFMA flash attention: one wave per (window, head) -------------------
// S^T = K @ Q^T via mfma(K_frag, Q_frag): lane owns q-row n = nt*16+(L&15);
// D-layout puts m at position g*4+q == the B-frag placement PV needs, so P
// feeds PV directly. V^T A-frags use the same placement. Split hi/lo on both.
__global__ __launch_bounds__(256, 2) void k_attn2(
    const unsigned short* __restrict__ Qh, const unsigned short* __restrict__ Ql,
    const float* __restrict__ biasT, const float* __restrict__ maskT,
    unsigned short* __restrict__ AWh, unsigned short* __restrict__ AWl,
    int win_base) {
  const int wid = threadIdx.x >> 6;
  const int L = threadIdx.x & 63;
  const int g = L >> 4, c = L & 15;
  int wh = blockIdx.x * 4 + wid;
  int w_loc = wh / 12, h = wh - w_loc * 12;
  int w_glob = win_base + w_loc;
  long tbase = (long)w_loc * NTOK * QKVN;
  int qoff = h * HD;
  const s16x8 z8 = {0, 0, 0, 0, 0, 0, 0, 0};

  s16x8 qh[7], ql[7];
#pragma unroll
  for (int nt = 0; nt < 7; nt++) {
    int n = nt * 16 + c;
    if (n < NTOK) {
      long a = tbase + (long)n * QKVN + qoff + g * 8;
      qh[nt] = *(const s16x8*)(Qh + a);
      ql[nt] = *(const s16x8*)(Ql + a);
    } else { qh[nt] = z8; ql[nt] = z8; }
  }
  const float* bT = biasT + (long)h * (NTOK * NTOK);
  const float* mT = maskT + (long)(w_glob & 255) * (NTOK * NTOK);

  f32x4 o[2][7];
  float mrun[7], lrun[7];
#pragma unroll
  for (int nt = 0; nt < 7; nt++) {
    o[0][nt] = (f32x4){0.f, 0.f, 0.f, 0.f};
    o[1][nt] = (f32x4){0.f, 0.f, 0.f, 0.f};
    mrun[nt] = -1e30f; lrun[nt] = 0.f;
  }

#pragma unroll
  for (int it = 0; it < 4; it++) {
    s16x8 kh[2], kl[2];
#pragma unroll
    for (int t = 0; t < 2; t++) {
      int m = it * 32 + t * 16 + c;
      if (m < NTOK) {
        long a = tbase + (long)m * QKVN + CDIM + qoff + g * 8;
        kh[t] = *(const s16x8*)(Qh + a);
        kl[t] = *(const s16x8*)(Ql + a);
      } else { kh[t] = z8; kl[t] = z8; }
    }
    s16x8 vh[2], vl[2];
#pragma unroll
    for (int dt = 0; dt < 2; dt++) {
#pragma unroll
      for (int e = 0; e < 8; e++) {
        int m = it * 32 + (e >> 2) * 16 + g * 4 + (e & 3);
        unsigned short hv = 0, lv = 0;
        if (m < NTOK) {
          long a = tbase + (long)m * QKVN + 2 * CDIM + qoff + dt * 16 + c;
          hv = Qh[a]; lv = Ql[a];
        }
        vh[dt][e] = (short)hv; vl[dt][e] = (short)lv;
      }
    }
#pragma unroll
    for (int nt = 0; nt < 7; nt++) {
      f32x4 s0 = (f32x4){0.f, 0.f, 0.f, 0.f};
      f32x4 s1 = (f32x4){0.f, 0.f, 0.f, 0.f};
      s0 = __builtin_amdgcn_mfma_f32_16x16x32_bf16(kh[0], qh[nt], s0, 0, 0, 0);
      s0 = __builtin_amdgcn_mfma_f32_16x16x32_bf16(kh[0], ql[nt], s0, 0, 0, 0);
      s0 = __builtin_amdgcn_mfma_f32_16x16x32_bf16(kl[0], qh[nt], s0, 0, 0, 0);
      s1 = __builtin_amdgcn_mfma_f32_16x16x32_bf16(kh[1], qh[nt], s1, 0, 0, 0);
      s1 = __builtin_amdgcn_mfma_f32_16x16x32_bf16(kh[1], ql[nt], s1, 0, 0, 0);
      s1 = __builtin_amdgcn_mfma_f32_16x16x32_bf16(kl[1], qh[nt], s1, 0, 0, 0);
      int n = nt * 16 + c;
      float sv[8]; float pm = -1e30f;
#pragma unroll
      for (int e = 0; e < 8; e++) {
        int m = it * 32 + (e >> 2) * 16 + g * 4 + (e & 3);
        float s = (e < 4) ? s0[e & 3] : s1[e & 3];
        if (m < NTOK) {
          if (n < NTOK) s += bT[m * NTOK + n] + mT[m * NTOK + n];
        } else s = -1e30f;
        sv[e] = s; pm = fmaxf(pm, s);
      }
      pm = fmaxf(pm, __shfl_xor(pm, 16));
      pm = fmaxf(pm, __shfl_xor(pm, 32));
      float mnew = fmaxf(mrun[nt], pm);
      float alpha = __expf(mrun[nt] - mnew);
      mrun[nt] = mnew;
      float ls = 0.f;
      s16x8 ph, pl;
#pragma unroll
      for (int e = 0; e < 8; e++) {
        float p = __expf(sv[e] - mnew);
        ls += p;
        unsigned short hh = bf_hi(p);
        ph[e] = (short)hh; pl[e] = (short)bf_hi(p - bf_f(hh));
      }
      ls += __shfl_xor(ls, 16);
      ls += __shfl_xor(ls, 32);
      lrun[nt] = lrun[nt] * alpha + ls;
      o[0][nt] *= alpha;
      o[1][nt] *= alpha;
      o[0][nt] = __builtin_amdgcn_mfma_f32_16x16x32_bf16(vh[0], ph, o[0][nt], 0, 0, 0);
      o[0][nt] = __builtin_amdgcn_mfma_f32_16x16x32_bf16(vh[0], pl, o[0][nt], 0, 0, 0);
      o[0][nt] = __builtin_amdgcn_mfma_f32_16x16x32_bf16(vl[0], ph, o[0][nt], 0, 0, 0);
      o[1][nt] = __builtin_amdgcn_mfma_f32_16x16x32_bf16(vh[1], ph, o[1][nt], 0, 0, 0);
      o[1][nt] = __builtin_amdgcn_mfma_f32_16x16x32_bf16(vh[1], pl, o[1][nt], 0, 0, 0);
      o[1][nt] = __builtin_amdgcn_mfma_f32_16x16x32_bf16(vl[1], ph, o[1][nt], 0, 0, 0);
    }
  }
#pragma unroll
  for (int nt = 0; nt < 7; nt++) {
    int n = nt * 16 + c;
    if (n >= NTOK) continue;
    float inv = 1.f / lrun[nt];
    long rowb = ((long)w_glob * NTOK + n) * CDIM + qoff;
#pragma unroll
    for (int dt = 0; dt < 2; dt++) {
      s16x4 hh, ll;
#pragma unroll
      for (int q = 0; q < 4; q++) {
        float v = o[dt][nt][q] * inv;
        unsigned short hv = bf_hi(v);
        hh[q] = (short)hv; ll[q] = (short)bf_hi(v - bf_f(hv));
      }
      *(s16x4*)(AWh + rowb + dt * 16 + g * 4) = hh;
      *(s16x4*)(AWl + rowb + dt * 16 + g * 4) = ll;
    }
  }
}

extern "C" void kernel_launch(void* const* d_in, const int* in_sizes, int n_in,
                              void* d_out, int out_size, void* d_ws, size_t ws_size,
                              hipStream_t stream) {
  const float* x     = (const float*)d_in[0];
  const float* mask  = (const float*)d_in[1];
  const float* n1g   = (const float*)d_in[2];
  const float* n1b   = (const float*)d_in[3];
  const float* qkvw  = (const float*)d_in[4];
  const float* qkvb  = (const float*)d_in[5];
  const float* btab  = (const float*)d_in[6];
  const float* projw = (const float*)d_in[7];
  const float* projb = (const float*)d_in[8];
  const float* n2g   = (const float*)d_in[9];
  const float* n2b   = (const float*)d_in[10];
  const float* fc1w  = (const float*)d_in[11];
  const float* fc1b  = (const float*)d_in[12];
  const float* fc2w  = (const float*)d_in[13];
  const float* fc2b  = (const float*)d_in[14];
  float* out = (float*)d_out;

  // ws: [XWh|XWl planes][shared region: QKV chunk planes / H single plane][weights][biasT|maskT]
  const long S1 = (long)TOK * CDIM;
  const long WELEMS = 442368L + 147456L + 589824L + 589824L;
  const long BMT = (long)(NHEAD + 256) * NTOK * NTOK;   // floats
  size_t base_b = 4ull * S1 + (size_t)WELEMS * 4 + (size_t)BMT * 4;
  size_t regA = (size_t)TOK * MLPH * 2;            // NCM=1 H full (>= NC=2 qkv chunk)
  size_t regB = (size_t)(TOK / 2) * MLPH * 2;      // NCM=2 (>= NC=4 qkv chunk)
  size_t regC = (size_t)(TOK / 4) * QKVN * 4;      // NCM=4, NC=4
  size_t regD = (size_t)(TOK / 8) * QKVN * 4;      // NCM=8, NC=8
  int NC, NCM; size_t region;
  if (base_b + regA <= ws_size)      { NCM = 1; NC = 2; region = regA; }
  else if (base_b + regB <= ws_size) { NCM = 2; NC = 4; region = regB; }
  else if (base_b + regC <= ws_size) { NCM = 4; NC = 4; region = regC; }
  else                               { NCM = 8; NC = 8; region = regD; }
  const int CH  = TOK / NC;    // qkv/attn chunk rows (mult of 128 & 98)
  const int CHM = TOK / NCM;   // MLP chunk rows

  char* b0 = (char*)d_ws;
  unsigned short* XWh = (unsigned short*)b0;
  unsigned short* XWl = XWh + S1;
  char* bB = b0 + 4 * S1;
  unsigned short* QKVh = (unsigned short*)bB;
  unsigned short* QKVl = QKVh + (long)CH * QKVN;
  unsigned short* Hh = (unsigned short*)bB;
  unsigned short* pW = (unsigned short*)(bB + region);
  unsigned short* Wqh = pW,            *Wql = Wqh + 442368;
  unsigned short* Wph = Wql + 442368,  *Wpl = Wph + 147456;
  unsigned short* W1h = Wpl + 147456,  *W1l = W1h + 589824;
  unsigned short* W2h = W1l + 589824,  *W2l = W2h + 589824;
  float* biasT = (float*)(pW + 2 * WELEMS);
  float* maskT = biasT + (long)NHEAD * NTOK * NTOK;

  // weight split+transpose (merged), bias/mask transpose
  k_prep<<<6912, 256, 0, stream>>>(qkvw, projw, fc1w, fc2w,
      Wqh, Wql, Wph, Wpl, W1h, W1l, W2h, W2l);
  k_bmT<<<(int)((BMT + 255) / 256), 256, 0, stream>>>(btab, mask, biasT, maskT);
  // LN1 + shift + window-partition gather -> XW hi/lo planes
  k_ln_bf<1, 1><<<TOK / 4, 256, 0, stream>>>(x, n1g, n1b, XWh, XWl);
  // attention path, chunked: qkv GEMM (planes, q pre-scaled) -> flash attn
  for (int c = 0; c < NC; c++) {
    long r0 = (long)c * CH;
    k_mfma<4, 1><<<9 * (CH / 128), 256, 0, stream>>>(XWh + r0 * CDIM, XWl + r0 * CDIM,
        Wqh, Wql, qkvb, QKVN, CDIM, nullptr, QKVh, QKVl, nullptr, 0);
    k_attn2<<<(CH / NTOK) * 3, 256, 0, stream>>>(QKVh, QKVl, biasT, maskT,
        XWh, XWl, (int)(r0 / NTOK));
  }
  // proj + window_reverse + roll + residual(x) -> d_out (spatial order)
  k_mfma<2, 1><<<3 * (TOK / 128), 256, 0, stream>>>(XWh, XWl, Wph, Wpl, projb,
      CDIM, CDIM, out, nullptr, nullptr, x, 0);
  // LN2 -> XWh single plane (fc1 is 2-pass, lo unused)
  k_ln_bf<0, 0><<<TOK / 4, 256, 0, stream>>>(out, n2g, n2b, XWh, nullptr);
  // MLP: fc1+gelu -> H single plane; fc2 + residual in-place on d_out
  for (int c = 0; c < NCM; c++) {
    long r0 = (long)c * CHM;
    k_mfma<5, 0><<<12 * (CHM / 128), 256, 0, stream>>>(XWh + r0 * CDIM, nullptr,
        W1h, W1l, fc1b, MLPH, CDIM, nullptr, Hh, nullptr, nullptr, 0);
    k_mfma<3, 0><<<3 * (CHM / 128), 256, 0, stream>>>(Hh, nullptr, W2h, W2l, fc2b,
        CDIM, MLPH, out, nullptr, nullptr, out, r0);
  }
}